// Round 1
// baseline (2119.068 us; speedup 1.0000x reference)
//
#include <hip/hip_runtime.h>

// Problem constants
#define BATCH 32
#define CIN   256
#define CHALF 128
#define NPIX  3136   // 56*56
#define MPOOL 784    // 28*28

// ---------------------------------------------------------------------------
// Kernel 1: fused 1x1 convs (channel matmul) + 2x2 max+avg pooling
// grid (8, 28, 32) = (out-group of 64, h2 row-pair, batch), block 256
// Writes:
//   c2o  [B][128][3136]  (full resolution, W2 conv)
//   c1p  [B][128][784]   (pooled W1 conv)
//   c3pT [B][784][256]   (pooled W3 conv, TRANSPOSED: m-major for PV loads)
// ---------------------------------------------------------------------------
__global__ __launch_bounds__(256) void k_conv_pool(
    const float* __restrict__ x,
    const float* __restrict__ W1,
    const float* __restrict__ W2,
    const float* __restrict__ W3,
    float* __restrict__ c2o,
    float* __restrict__ c1p,
    float* __restrict__ c3pT)
{
    const int og = blockIdx.x;   // 0..7 : 64-out-channel group of Wcat[512]
    const int h2 = blockIdx.y;   // 0..27: pooled row
    const int b  = blockIdx.z;
    const int t  = threadIdx.x;
    const int tx = t & 15, ty = t >> 4;

    __shared__ float Wt[64][33];    // padded
    __shared__ float Xt[32][113];   // padded; 112 pixels = rows 2h2,2h2+1
    __shared__ float Ys[64][113];

    const float* Wsrc;
    int o_base;
    if (og < 2)      { Wsrc = W1; o_base = og * 64; }
    else if (og < 4) { Wsrc = W2; o_base = (og - 2) * 64; }
    else             { Wsrc = W3; o_base = (og - 4) * 64; }

    float acc[4][7];
    #pragma unroll
    for (int i = 0; i < 4; ++i)
        #pragma unroll
        for (int j = 0; j < 7; ++j) acc[i][j] = 0.f;

    // rows 2h2 and 2h2+1 are contiguous: 112 floats starting at h2*112
    const float* xb = x + (size_t)b * CIN * NPIX + h2 * 112;

    for (int kc = 0; kc < CIN; kc += 32) {
        __syncthreads();
        // load W tile 64x32 (coalesced 32-float runs)
        #pragma unroll
        for (int i = 0; i < 8; ++i) {
            int idx = t + i * 256;
            int o = idx >> 5, k = idx & 31;
            Wt[o][k] = Wsrc[(o_base + o) * CIN + kc + k];
        }
        // load X tile 32x112 (coalesced 112-float runs)
        #pragma unroll
        for (int i = 0; i < 14; ++i) {
            int idx = t + i * 256;
            int k = idx / 112, px = idx % 112;
            Xt[k][px] = xb[(size_t)(kc + k) * NPIX + px];
        }
        __syncthreads();
        #pragma unroll 4
        for (int k = 0; k < 32; ++k) {
            float wv[4], xv[7];
            #pragma unroll
            for (int i = 0; i < 4; ++i) wv[i] = Wt[ty + 16 * i][k];
            #pragma unroll
            for (int j = 0; j < 7; ++j) xv[j] = Xt[k][tx + 16 * j];
            #pragma unroll
            for (int i = 0; i < 4; ++i)
                #pragma unroll
                for (int j = 0; j < 7; ++j)
                    acc[i][j] = fmaf(wv[i], xv[j], acc[i][j]);
        }
    }

    // stash tile in LDS for epilogue reshuffle
    __syncthreads();
    #pragma unroll
    for (int i = 0; i < 4; ++i)
        #pragma unroll
        for (int j = 0; j < 7; ++j)
            Ys[ty + 16 * i][tx + 16 * j] = acc[i][j];
    __syncthreads();

    if (og == 2 || og == 3) {
        // c2: full resolution, coalesced 112-float runs
        float* dst = c2o + ((size_t)b * CHALF + (og - 2) * 64) * NPIX + h2 * 112;
        #pragma unroll
        for (int i = 0; i < 28; ++i) {
            int idx = t + i * 256;
            int o = idx / 112, px = idx % 112;
            dst[(size_t)o * NPIX + px] = Ys[o][px];
        }
    } else if (og < 2) {
        // c1 pooled: [b][o][m], o-major mapping so m runs coalesce
        float* dst = c1p + ((size_t)b * CHALF + og * 64) * MPOOL + h2 * 28;
        #pragma unroll
        for (int i = 0; i < 7; ++i) {
            int idx = t + i * 256;
            int o = idx / 28, w2 = idx % 28;
            float p0 = Ys[o][2 * w2],      p1 = Ys[o][2 * w2 + 1];
            float p2 = Ys[o][56 + 2 * w2], p3 = Ys[o][56 + 2 * w2 + 1];
            float mx = fmaxf(fmaxf(p0, p1), fmaxf(p2, p3));
            float av = (p0 + p1 + p2 + p3) * 0.25f;
            dst[(size_t)o * MPOOL + w2] = mx + av;
        }
    } else {
        // c3 pooled TRANSPOSED: [b][m][c], c-major mapping so c runs coalesce
        int cc0 = (og - 4) * 64;
        float* dst = c3pT + ((size_t)b * MPOOL + h2 * 28) * CIN + cc0;
        #pragma unroll
        for (int i = 0; i < 7; ++i) {
            int idx = t + i * 256;
            int w2 = idx >> 6, o = idx & 63;
            float p0 = Ys[o][2 * w2],      p1 = Ys[o][2 * w2 + 1];
            float p2 = Ys[o][56 + 2 * w2], p3 = Ys[o][56 + 2 * w2 + 1];
            float mx = fmaxf(fmaxf(p0, p1), fmaxf(p2, p3));
            float av = (p0 + p1 + p2 + p3) * 0.25f;
            dst[(size_t)w2 * CIN + o] = mx + av;
        }
    }
}

// ---------------------------------------------------------------------------
// Kernel 2: fused scores -> softmax -> PV -> gamma*refined + x
// grid (196, 32) = (n-tile of 16, batch), block 256
// ---------------------------------------------------------------------------
__global__ __launch_bounds__(256) void k_attn(
    const float* __restrict__ c2o,
    const float* __restrict__ c1p,
    const float* __restrict__ c3pT,
    const float* __restrict__ x,
    const float* __restrict__ gamma,
    float* __restrict__ out)
{
    const int nb = blockIdx.x;          // n tile index
    const int b  = blockIdx.y;
    const int n_base = nb * 16;
    const int t = threadIdx.x;

    __shared__ float sc[16][788];       // scores / exp(scores), padded
    __shared__ float c2sT[128][16];     // c2[b][c][n_base+ln] transposed
    __shared__ float pool[16 * 272];    // stage buffer (c3pT chunks / out transpose)
    __shared__ float rinv[16];

    // phase 0: load the 16 c2 columns, transposed into LDS
    #pragma unroll
    for (int i = 0; i < 8; ++i) {
        int idx = t + i * 256;
        int c = idx >> 4, ln = idx & 15;
        c2sT[c][ln] = c2o[((size_t)b * CHALF + c) * NPIX + n_base + ln];
    }
    __syncthreads();

    // phase 1: scores[n][m] = sum_c c2sT[c][n] * c1p[b][c][m]
    {
        const int ml = t & 127;         // m lane (float2 -> 256 m per sweep)
        const int ng = t >> 7;          // n group: 8 n's each
        const float* c1pb = c1p + (size_t)b * CHALF * MPOOL;
        for (int i = 0; i < 4; ++i) {
            int m0 = 2 * ml + 256 * i;
            if (m0 < MPOOL) {
                float a[2][8];
                #pragma unroll
                for (int mi = 0; mi < 2; ++mi)
                    #pragma unroll
                    for (int k = 0; k < 8; ++k) a[mi][k] = 0.f;
                #pragma unroll 2
                for (int c = 0; c < CHALF; ++c) {
                    float2 cv = *(const float2*)(c1pb + (size_t)c * MPOOL + m0);
                    float4 w0 = *(const float4*)(&c2sT[c][ng * 8]);
                    float4 w1 = *(const float4*)(&c2sT[c][ng * 8 + 4]);
                    const float* w = (const float*)&w0;
                    #pragma unroll
                    for (int k = 0; k < 4; ++k) {
                        a[0][k] = fmaf(cv.x, w[k], a[0][k]);
                        a[1][k] = fmaf(cv.y, w[k], a[1][k]);
                    }
                    const float* w2p = (const float*)&w1;
                    #pragma unroll
                    for (int k = 0; k < 4; ++k) {
                        a[0][4 + k] = fmaf(cv.x, w2p[k], a[0][4 + k]);
                        a[1][4 + k] = fmaf(cv.y, w2p[k], a[1][4 + k]);
                    }
                }
                #pragma unroll
                for (int k = 0; k < 8; ++k) {
                    sc[ng * 8 + k][m0]     = a[0][k];
                    sc[ng * 8 + k][m0 + 1] = a[1][k];
                }
            }
        }
    }
    __syncthreads();

    // phase 2: wave-parallel softmax over m (store unnormalized exp; defer 1/sum)
    {
        const int wave = t >> 6, lane = t & 63;
        for (int r = wave * 4; r < wave * 4 + 4; ++r) {
            float mx = -1e30f;
            for (int i = 0; i < 13; ++i) {
                int m = lane + 64 * i;
                if (m < MPOOL) mx = fmaxf(mx, sc[r][m]);
            }
            #pragma unroll
            for (int off = 32; off; off >>= 1) mx = fmaxf(mx, __shfl_xor(mx, off));
            float s = 0.f;
            for (int i = 0; i < 13; ++i) {
                int m = lane + 64 * i;
                if (m < MPOOL) {
                    float e = __expf(sc[r][m] - mx);
                    sc[r][m] = e;
                    s += e;
                }
            }
            #pragma unroll
            for (int off = 32; off; off >>= 1) s += __shfl_xor(s, off);
            if (lane == 0) rinv[r] = 1.f / s;
        }
    }

    // phase 3: refined[c][n] = sum_m c3pT[m][c] * exp_sc[n][m]  (scale later)
    const int cq = t & 63, ng3 = t >> 6;
    const int c0 = cq * 4, nn0 = ng3 * 4;
    float racc[4][4];
    #pragma unroll
    for (int ci = 0; ci < 4; ++ci)
        #pragma unroll
        for (int j = 0; j < 4; ++j) racc[ci][j] = 0.f;

    const float* c3b = c3pT + (size_t)b * MPOOL * CIN;
    for (int mc = 0; mc < MPOOL; mc += 16) {
        __syncthreads();
        #pragma unroll
        for (int i = 0; i < 16; ++i) {
            int idx = t + i * 256;
            int mr = idx >> 8, c = idx & 255;
            pool[mr * 256 + c] = c3b[(size_t)(mc + mr) * CIN + c];
        }
        __syncthreads();
        #pragma unroll 4
        for (int mr = 0; mr < 16; ++mr) {
            float4 cv = *(const float4*)(&pool[mr * 256 + c0]);
            const float* cvf = (const float*)&cv;
            float av[4];
            #pragma unroll
            for (int j = 0; j < 4; ++j) av[j] = sc[nn0 + j][mc + mr];
            #pragma unroll
            for (int ci = 0; ci < 4; ++ci)
                #pragma unroll
                for (int j = 0; j < 4; ++j)
                    racc[ci][j] = fmaf(cvf[ci], av[j], racc[ci][j]);
        }
    }

    // epilogue: normalize, transpose via LDS, coalesced gamma*refined + x
    __syncthreads();
    // rbuf layout [16][257]: rbuf[ln][c]
    #pragma unroll
    for (int j = 0; j < 4; ++j) {
        float ri = rinv[nn0 + j];
        #pragma unroll
        for (int ci = 0; ci < 4; ++ci)
            pool[(nn0 + j) * 257 + c0 + ci] = racc[ci][j] * ri;
    }
    __syncthreads();
    const float g = gamma[0];
    #pragma unroll
    for (int i = 0; i < 16; ++i) {
        int idx = t + i * 256;
        int c = idx >> 4, ln = idx & 15;
        size_t off = ((size_t)b * CIN + c) * NPIX + n_base + ln;
        out[off] = g * pool[ln * 257 + c] + x[off];
    }
}

extern "C" void kernel_launch(void* const* d_in, const int* in_sizes, int n_in,
                              void* d_out, int out_size, void* d_ws, size_t ws_size,
                              hipStream_t stream) {
    const float* x     = (const float*)d_in[0];
    const float* W1    = (const float*)d_in[1];
    const float* W2    = (const float*)d_in[2];
    const float* W3    = (const float*)d_in[3];
    const float* gamma = (const float*)d_in[4];
    float* out = (float*)d_out;

    float* ws   = (float*)d_ws;
    float* c2o  = ws;                                      // 32*128*3136
    float* c1p  = c2o + (size_t)BATCH * CHALF * NPIX;      // 32*128*784
    float* c3pT = c1p + (size_t)BATCH * CHALF * MPOOL;     // 32*784*256

    dim3 g1(8, 28, BATCH);
    k_conv_pool<<<g1, 256, 0, stream>>>(x, W1, W2, W3, c2o, c1p, c3pT);
    dim3 g2(196, BATCH);
    k_attn<<<g2, 256, 0, stream>>>(c2o, c1p, c3pT, x, gamma, out);
}

// Round 2
// 830.587 us; speedup vs baseline: 2.5513x; 2.5513x over previous
//
#include <hip/hip_runtime.h>

#define BATCH 32
#define CIN   256
#define CHALF 128
#define NPIX  3136   // 56*56
#define MPOOL 784    // 28*28
#define MPAD  896    // 784 padded to multiple of 32 (PV K-dim), 56 frags of 16

typedef __bf16 bf16;
typedef __bf16 bf16x8 __attribute__((ext_vector_type(8)));
typedef float  f32x4  __attribute__((ext_vector_type(4)));

// ---------------------------------------------------------------------------
// Kernel 1: fused 1x1 convs (channel matmul) + 2x2 max+avg pooling.
// fp32 VALU compute, bf16 MFMA-ready outputs:
//   c2n  [b][3136 n][128 c]   (scores A operand: row n, 8 contiguous c/lane)
//   c1pT [b][896 m][128 c]    (scores B operand; m 784..895 zeroed)
//   c3p  [b][256 c][896 m]    (PV B operand; m 784..895 zeroed)
// grid (8, 28, 32) = (out-group of 64, pooled row h2, batch), block 256
// ---------------------------------------------------------------------------
__global__ __launch_bounds__(256) void k_conv_pool(
    const float* __restrict__ x,
    const float* __restrict__ W1,
    const float* __restrict__ W2,
    const float* __restrict__ W3,
    bf16* __restrict__ c2n,
    bf16* __restrict__ c1pT,
    bf16* __restrict__ c3p)
{
    const int og = blockIdx.x;
    const int h2 = blockIdx.y;
    const int b  = blockIdx.z;
    const int t  = threadIdx.x;
    const int tx = t & 15, ty = t >> 4;

    __shared__ float Wt[64][33];
    __shared__ float Xt[32][113];
    __shared__ float Ys[64][113];

    const float* Wsrc;
    int o_base;
    if (og < 2)      { Wsrc = W1; o_base = og * 64; }
    else if (og < 4) { Wsrc = W2; o_base = (og - 2) * 64; }
    else             { Wsrc = W3; o_base = (og - 4) * 64; }

    float acc[4][7];
    #pragma unroll
    for (int i = 0; i < 4; ++i)
        #pragma unroll
        for (int j = 0; j < 7; ++j) acc[i][j] = 0.f;

    const float* xb = x + (size_t)b * CIN * NPIX + h2 * 112;

    for (int kc = 0; kc < CIN; kc += 32) {
        __syncthreads();
        #pragma unroll
        for (int i = 0; i < 8; ++i) {
            int idx = t + i * 256;
            int o = idx >> 5, k = idx & 31;
            Wt[o][k] = Wsrc[(o_base + o) * CIN + kc + k];
        }
        #pragma unroll
        for (int i = 0; i < 14; ++i) {
            int idx = t + i * 256;
            int k = idx / 112, px = idx % 112;
            Xt[k][px] = xb[(size_t)(kc + k) * NPIX + px];
        }
        __syncthreads();
        #pragma unroll 4
        for (int k = 0; k < 32; ++k) {
            float wv[4], xv[7];
            #pragma unroll
            for (int i = 0; i < 4; ++i) wv[i] = Wt[ty + 16 * i][k];
            #pragma unroll
            for (int j = 0; j < 7; ++j) xv[j] = Xt[k][tx + 16 * j];
            #pragma unroll
            for (int i = 0; i < 4; ++i)
                #pragma unroll
                for (int j = 0; j < 7; ++j)
                    acc[i][j] = fmaf(wv[i], xv[j], acc[i][j]);
        }
    }

    __syncthreads();
    #pragma unroll
    for (int i = 0; i < 4; ++i)
        #pragma unroll
        for (int j = 0; j < 7; ++j)
            Ys[ty + 16 * i][tx + 16 * j] = acc[i][j];
    __syncthreads();

    if (og == 2 || og == 3) {
        // c2n [n][c]: full res, n = h2*112 + px
        bf16* dst = c2n + (size_t)b * NPIX * CHALF + (og - 2) * 64;
        #pragma unroll
        for (int i = 0; i < 28; ++i) {
            int idx = t + i * 256;          // 64 o x 112 px
            int px = idx >> 6, o = idx & 63;
            dst[(size_t)(h2 * 112 + px) * CHALF + o] = (bf16)Ys[o][px];
        }
    } else if (og < 2) {
        // c1pT [m][c], m = h2*28 + w2
        bf16* dst = c1pT + (size_t)b * MPAD * CHALF + og * 64;
        #pragma unroll
        for (int i = 0; i < 7; ++i) {
            int idx = t + i * 256;          // 28 w2 x 64 o
            int w2 = idx >> 6, o = idx & 63;
            float p0 = Ys[o][2 * w2],      p1 = Ys[o][2 * w2 + 1];
            float p2 = Ys[o][56 + 2 * w2], p3 = Ys[o][56 + 2 * w2 + 1];
            float mx = fmaxf(fmaxf(p0, p1), fmaxf(p2, p3));
            float av = (p0 + p1 + p2 + p3) * 0.25f;
            dst[(size_t)(h2 * 28 + w2) * CHALF + o] = (bf16)(mx + av);
        }
        if (og == 0) {
            // zero pads (deterministic every call; ws is poisoned once)
            bf16* pz = c1pT + (size_t)b * MPAD * CHALF + (size_t)MPOOL * CHALF;
            #pragma unroll
            for (int i = 0; i < 2; ++i) {   // 112*128 = 14336 / 28 blocks = 512
                int idx = h2 * 512 + t + i * 256;
                pz[idx] = (bf16)0.f;
            }
            bf16* cz = c3p + (size_t)b * CIN * MPAD;
            #pragma unroll
            for (int i = 0; i < 4; ++i) {   // 256*112 = 28672 / 28 = 1024
                int idx = h2 * 1024 + t + i * 256;
                int c = idx / 112, mp = idx - c * 112;
                cz[(size_t)c * MPAD + MPOOL + mp] = (bf16)0.f;
            }
        }
    } else {
        // c3p [c][m], m = h2*28 + w2
        int cc0 = (og - 4) * 64;
        bf16* dst = c3p + (size_t)b * CIN * MPAD + (size_t)cc0 * MPAD + h2 * 28;
        #pragma unroll
        for (int i = 0; i < 7; ++i) {
            int idx = t + i * 256;          // 64 o x 28 w2
            int o = idx / 28, w2 = idx - o * 28;
            float p0 = Ys[o][2 * w2],      p1 = Ys[o][2 * w2 + 1];
            float p2 = Ys[o][56 + 2 * w2], p3 = Ys[o][56 + 2 * w2 + 1];
            float mx = fmaxf(fmaxf(p0, p1), fmaxf(p2, p3));
            float av = (p0 + p1 + p2 + p3) * 0.25f;
            dst[(size_t)o * MPAD + w2] = (bf16)(mx + av);
        }
    }
}

// ---------------------------------------------------------------------------
// Kernel 2: MFMA scores -> softmax -> MFMA PV -> gamma*refined + x
// block = 512 threads (8 waves), per (64-row n-tile, batch)
// grid (49, 32)
// LDS: S tile [64 n][896 m] bf16, XOR-swizzled (byte ^= (n&7)<<4) = 112 KB
//      reused as fp32 [64][257] for the output transpose.
// ---------------------------------------------------------------------------
__global__ __launch_bounds__(512, 2) void k_attn(
    const bf16* __restrict__ c2n,
    const bf16* __restrict__ c1pT,
    const bf16* __restrict__ c3p,
    const float* __restrict__ x,
    const float* __restrict__ gamma,
    float* __restrict__ out)
{
    const int nb = blockIdx.x, b = blockIdx.y;
    const int n0 = nb * 64;
    const int t = threadIdx.x;
    const int lane = t & 63, wave = t >> 6;
    const int l15 = lane & 15, lg = lane >> 4;
    const int wn = wave >> 2, wq = wave & 3;   // wq: m-split (S) / c-split (PV)

    __shared__ __align__(16) unsigned char smem[114688];
    float* R = (float*)smem;                    // epilogue [64][257]

    // ---------------- Phase S: S[64n][896m] = c2n(64x128) * c1pT^T ----------
    bf16x8 afr[2][4];
    {
        const bf16* base = c2n + (size_t)b * NPIX * CHALF;
        #pragma unroll
        for (int fn = 0; fn < 2; ++fn) {
            int n = n0 + wn * 32 + fn * 16 + l15;
            #pragma unroll
            for (int k = 0; k < 4; ++k)
                afr[fn][k] = *(const bf16x8*)(base + (size_t)n * CHALF + k * 32 + lg * 8);
        }
    }
    f32x4 acc[2][14];
    #pragma unroll
    for (int fn = 0; fn < 2; ++fn)
        #pragma unroll
        for (int mf = 0; mf < 14; ++mf) {
            f32x4 z = {0.f, 0.f, 0.f, 0.f};
            acc[fn][mf] = z;
        }

    const bf16* c1b = c1pT + (size_t)b * MPAD * CHALF;
    for (int mf = 0; mf < 14; ++mf) {
        int m = wq * 224 + mf * 16 + l15;
        #pragma unroll
        for (int k = 0; k < 4; ++k) {
            bf16x8 bfr = *(const bf16x8*)(c1b + (size_t)m * CHALF + k * 32 + lg * 8);
            acc[0][mf] = __builtin_amdgcn_mfma_f32_16x16x32_bf16(afr[0][k], bfr, acc[0][mf], 0, 0, 0);
            acc[1][mf] = __builtin_amdgcn_mfma_f32_16x16x32_bf16(afr[1][k], bfr, acc[1][mf], 0, 0, 0);
        }
    }
    // D layout: col m = l15, rows n = lg*4 + r. Write bf16 swizzled.
    #pragma unroll
    for (int fn = 0; fn < 2; ++fn)
        #pragma unroll
        for (int mf = 0; mf < 14; ++mf) {
            int m = wq * 224 + mf * 16 + l15;
            #pragma unroll
            for (int r = 0; r < 4; ++r) {
                int n = wn * 32 + fn * 16 + lg * 4 + r;
                int byte = (n * 1792 + m * 2) ^ ((n & 7) << 4);
                *(bf16*)(smem + byte) = (bf16)acc[fn][mf][r];
            }
        }
    __syncthreads();

    // ---------------- softmax over m (8 rows per wave) ----------------------
    for (int rr = 0; rr < 8; ++rr) {
        int n = wave * 8 + rr;
        int rowbase = n * 1792, sw = (n & 7) << 4;
        float v[13];
        float mx = -1e30f;
        #pragma unroll
        for (int i = 0; i < 13; ++i) {
            int m = lane + 64 * i;
            v[i] = (m < MPOOL) ? (float)*(const bf16*)(smem + ((rowbase + 2 * m) ^ sw))
                               : -1e30f;
            mx = fmaxf(mx, v[i]);
        }
        #pragma unroll
        for (int off = 32; off; off >>= 1) mx = fmaxf(mx, __shfl_xor(mx, off));
        float s = 0.f;
        float e[13];
        #pragma unroll
        for (int i = 0; i < 13; ++i) {
            int m = lane + 64 * i;
            e[i] = (m < MPOOL) ? __expf(v[i] - mx) : 0.f;
            s += e[i];
        }
        #pragma unroll
        for (int off = 32; off; off >>= 1) s += __shfl_xor(s, off);
        float ri = 1.f / s;
        #pragma unroll
        for (int i = 0; i < 14; ++i) {          // write all 896 incl pad
            int m = lane + 64 * i;
            float pv = (i < 13) ? e[i] * ri : 0.f;
            *(bf16*)(smem + ((rowbase + 2 * m) ^ sw)) = (bf16)pv;
        }
    }
    __syncthreads();

    // ---------------- Phase PV: refined[n][c] = P(64x896) * c3p^T -----------
    f32x4 acc2[2][4];
    #pragma unroll
    for (int fn = 0; fn < 2; ++fn)
        #pragma unroll
        for (int fc = 0; fc < 4; ++fc) {
            f32x4 z = {0.f, 0.f, 0.f, 0.f};
            acc2[fn][fc] = z;
        }
    const bf16* c3b = c3p + (size_t)b * CIN * MPAD;
    for (int ks = 0; ks < 28; ++ks) {
        int m0 = ks * 32 + lg * 8;
        bf16x8 af[2];
        #pragma unroll
        for (int fn = 0; fn < 2; ++fn) {
            int n = wn * 32 + fn * 16 + l15;
            int byte = (n * 1792 + m0 * 2) ^ ((n & 7) << 4);
            af[fn] = *(const bf16x8*)(smem + byte);
        }
        #pragma unroll
        for (int fc = 0; fc < 4; ++fc) {
            int c = wq * 64 + fc * 16 + l15;
            bf16x8 bfr = *(const bf16x8*)(c3b + (size_t)c * MPAD + m0);
            acc2[0][fc] = __builtin_amdgcn_mfma_f32_16x16x32_bf16(af[0], bfr, acc2[0][fc], 0, 0, 0);
            acc2[1][fc] = __builtin_amdgcn_mfma_f32_16x16x32_bf16(af[1], bfr, acc2[1][fc], 0, 0, 0);
        }
    }

    // ---------------- epilogue: transpose via LDS, out = g*refined + x ------
    __syncthreads();   // all PV reads of S done before overwrite
    #pragma unroll
    for (int fn = 0; fn < 2; ++fn)
        #pragma unroll
        for (int fc = 0; fc < 4; ++fc) {
            int c = wq * 64 + fc * 16 + l15;
            #pragma unroll
            for (int r = 0; r < 4; ++r) {
                int n = wn * 32 + fn * 16 + lg * 4 + r;
                R[n * 257 + c] = acc2[fn][fc][r];
            }
        }
    __syncthreads();
    const float g = gamma[0];
    const float* xb = x + (size_t)b * CIN * NPIX + n0;
    float* ob = out + (size_t)b * CIN * NPIX + n0;
    #pragma unroll 4
    for (int i = 0; i < 32; ++i) {
        int idx = t + i * 512;                  // 256 c x 64 n
        int c = idx >> 6, nn = idx & 63;
        size_t off = (size_t)c * NPIX + nn;
        ob[off] = g * R[nn * 257 + c] + xb[off];
    }
}

extern "C" void kernel_launch(void* const* d_in, const int* in_sizes, int n_in,
                              void* d_out, int out_size, void* d_ws, size_t ws_size,
                              hipStream_t stream) {
    const float* x     = (const float*)d_in[0];
    const float* W1    = (const float*)d_in[1];
    const float* W2    = (const float*)d_in[2];
    const float* W3    = (const float*)d_in[3];
    const float* gamma = (const float*)d_in[4];
    float* out = (float*)d_out;

    bf16* ws   = (bf16*)d_ws;
    bf16* c2n  = ws;                                       // 32*3136*128
    bf16* c1pT = c2n + (size_t)BATCH * NPIX * CHALF;       // 32*896*128
    bf16* c3p  = c1pT + (size_t)BATCH * MPAD * CHALF;      // 32*256*896

    dim3 g1(8, 28, BATCH);
    k_conv_pool<<<g1, 256, 0, stream>>>(x, W1, W2, W3, c2n, c1pT, c3p);
    dim3 g2(49, BATCH);
    k_attn<<<g2, 512, 0, stream>>>(c2n, c1pT, c3p, x, gamma, out);
}

// Round 3
// 434.719 us; speedup vs baseline: 4.8746x; 1.9106x over previous
//
#include <hip/hip_runtime.h>

#define BATCH 32
#define CIN   256
#define CHALF 128
#define NPIX  3136   // 56*56
#define MPOOL 784    // 28*28
#define MPAD  896    // 784 padded to multiple of 32 (PV K-dim)

typedef __bf16 bf16;
typedef __bf16 bf16x2 __attribute__((ext_vector_type(2)));
typedef __bf16 bf16x4 __attribute__((ext_vector_type(4)));
typedef __bf16 bf16x8 __attribute__((ext_vector_type(8)));
typedef float  f32x4  __attribute__((ext_vector_type(4)));

// ---------------------------------------------------------------------------
// k_cast: W1[128][256], W2[128][256], W3[256][256] fp32 -> Wcat[512][256] bf16
// grid 128 x 256 threads, 1 float4 per thread
// ---------------------------------------------------------------------------
__global__ __launch_bounds__(256) void k_cast(
    const float* __restrict__ W1, const float* __restrict__ W2,
    const float* __restrict__ W3, bf16* __restrict__ Wcat)
{
    int u = blockIdx.x * 256 + threadIdx.x;   // 32768 units
    int o = u >> 6, k4 = (u & 63) * 4;
    const float* src = (o < 128) ? (W1 + o * 256)
                     : (o < 256) ? (W2 + (o - 128) * 256)
                                 : (W3 + (o - 256) * 256);
    float4 v = *(const float4*)(src + k4);
    bf16x4 w = { (bf16)v.x, (bf16)v.y, (bf16)v.z, (bf16)v.w };
    *(bf16x4*)(Wcat + o * 256 + k4) = w;
}

// ---------------------------------------------------------------------------
// k_conv: Y[512 o][112 n] = Wcat * x-slice via MFMA, fused 2x2 max+avg pool.
// grid (28 h2, 32 b), 512 threads (8 waves, wave w owns o in [w*64, w*64+64)).
// LDS phase 1: xs[112 n][264 c] bf16 (stride 528 B, 16B-aligned frag reads)
// LDS phase 2 (reuse): slab[112 n][260 o] bf16 (stride 520 B), 2 o-rounds
// Outputs: c2n [b][n][128c], c1pT [b][m][128c], c3p [b][256c][m] (m-pad zeroed)
// ---------------------------------------------------------------------------
#define XS_STRIDE   528
#define SLAB_STRIDE 520

__global__ __launch_bounds__(512) void k_conv(
    const float* __restrict__ x, const bf16* __restrict__ Wcat,
    bf16* __restrict__ c2n, bf16* __restrict__ c1pT, bf16* __restrict__ c3p)
{
    const int h2 = blockIdx.x, b = blockIdx.y;
    const int t = threadIdx.x;
    const int lane = t & 63, wave = t >> 6;
    const int l15 = lane & 15, lg = lane >> 4;

    __shared__ __align__(16) unsigned char smem[59136];

    // zero m-pads (deterministic each call)
    if (h2 == 0) {
        float4 z = {0.f, 0.f, 0.f, 0.f};
        float4* p1 = (float4*)(c1pT + (size_t)b * MPAD * CHALF + (size_t)MPOOL * CHALF);
        for (int u = t; u < 1792; u += 512) p1[u] = z;   // 112*128 bf16
        bf16* p3 = c3p + (size_t)b * CIN * MPAD + MPOOL;
        for (int u = t; u < 256 * 14; u += 512) {
            int c = u / 14, g = u % 14;
            *(float4*)((char*)(p3 + (size_t)c * MPAD) + g * 16) = z;
        }
    }

    // ---- stage x slice: [112 n][256 c] bf16, transposed convert ----
    {
        const float* xb = x + (size_t)b * CIN * NPIX + h2 * 112;
        float vv[14][4];
        #pragma unroll
        for (int i = 0; i < 14; ++i) {
            int u = t + i * 512;               // 7168 units: (c4, n)
            int c4 = u / 112, n = u - c4 * 112;
            const float* s = xb + (size_t)(c4 * 4) * NPIX + n;
            vv[i][0] = s[0];
            vv[i][1] = s[NPIX];
            vv[i][2] = s[2 * NPIX];
            vv[i][3] = s[3 * NPIX];
        }
        #pragma unroll
        for (int i = 0; i < 14; ++i) {
            int u = t + i * 512;
            int c4 = u / 112, n = u - c4 * 112;
            bf16x4 w = {(bf16)vv[i][0], (bf16)vv[i][1], (bf16)vv[i][2], (bf16)vv[i][3]};
            *(bf16x4*)(smem + n * XS_STRIDE + c4 * 8) = w;
        }
    }
    __syncthreads();

    // ---- MFMA K-loop: wave tile 64o x 112n, K = 256 ----
    f32x4 acc[4][7];
    #pragma unroll
    for (int fo = 0; fo < 4; ++fo)
        #pragma unroll
        for (int fn = 0; fn < 7; ++fn) {
            f32x4 zz = {0.f, 0.f, 0.f, 0.f};
            acc[fo][fn] = zz;
        }
    {
        const int o0 = wave * 64;
        const bf16* wbase = Wcat + (size_t)(o0 + l15) * 256 + lg * 8;
        const unsigned char* xsb = smem + l15 * XS_STRIDE + lg * 16;
        for (int ks = 0; ks < 8; ++ks) {
            bf16x8 afr[4], bfr[7];
            #pragma unroll
            for (int fo = 0; fo < 4; ++fo)
                afr[fo] = *(const bf16x8*)(wbase + fo * 16 * 256 + ks * 32);
            #pragma unroll
            for (int fn = 0; fn < 7; ++fn)
                bfr[fn] = *(const bf16x8*)(xsb + fn * 16 * XS_STRIDE + ks * 64);
            #pragma unroll
            for (int fo = 0; fo < 4; ++fo)
                #pragma unroll
                for (int fn = 0; fn < 7; ++fn)
                    acc[fo][fn] = __builtin_amdgcn_mfma_f32_16x16x32_bf16(
                        afr[fo], bfr[fn], acc[fo][fn], 0, 0, 0);
        }
    }

    // ---- epilogue round A: o 0..255 (c1 pooled + c2 full-res) ----
    __syncthreads();
    if (wave < 4) {
        #pragma unroll
        for (int fo = 0; fo < 4; ++fo)
            #pragma unroll
            for (int fn = 0; fn < 7; ++fn) {
                int n = fn * 16 + l15;
                int ol = wave * 64 + fo * 16 + lg * 4;
                f32x4 a = acc[fo][fn];
                bf16x4 w = {(bf16)a[0], (bf16)a[1], (bf16)a[2], (bf16)a[3]};
                *(bf16x4*)(smem + n * SLAB_STRIDE + ol * 2) = w;
            }
    }
    __syncthreads();
    {   // c1pT[m][128c], pooled from slab o 0..127
        bf16* dst = c1pT + (size_t)b * MPAD * CHALF + (size_t)h2 * 28 * CHALF;
        for (int u = t; u < 896; u += 512) {
            int w2 = u >> 5, o4 = (u & 31) * 4;
            bf16x4 r0 = *(bf16x4*)(smem + (2 * w2)      * SLAB_STRIDE + o4 * 2);
            bf16x4 r1 = *(bf16x4*)(smem + (2 * w2 + 1)  * SLAB_STRIDE + o4 * 2);
            bf16x4 r2 = *(bf16x4*)(smem + (56 + 2 * w2) * SLAB_STRIDE + o4 * 2);
            bf16x4 r3 = *(bf16x4*)(smem + (57 + 2 * w2) * SLAB_STRIDE + o4 * 2);
            bf16x4 o_;
            #pragma unroll
            for (int j = 0; j < 4; ++j) {
                float p0 = (float)r0[j], p1 = (float)r1[j];
                float p2 = (float)r2[j], p3 = (float)r3[j];
                float mx = fmaxf(fmaxf(p0, p1), fmaxf(p2, p3));
                float av = (p0 + p1 + p2 + p3) * 0.25f;
                o_[j] = (bf16)(mx + av);
            }
            *(bf16x4*)(dst + (size_t)w2 * CHALF + o4) = o_;
        }
    }
    {   // c2n[n][128c] from slab o 128..255
        bf16* dst = c2n + (size_t)b * NPIX * CHALF + (size_t)h2 * 112 * CHALF;
        for (int u = t; u < 3584; u += 512) {
            int n = u >> 5, o4 = (u & 31) * 4;
            bf16x4 v = *(bf16x4*)(smem + n * SLAB_STRIDE + 256 + o4 * 2);
            *(bf16x4*)(dst + (size_t)n * CHALF + o4) = v;
        }
    }

    // ---- epilogue round B: o 256..511 (c3 pooled, [c][m]) ----
    __syncthreads();
    if (wave >= 4) {
        #pragma unroll
        for (int fo = 0; fo < 4; ++fo)
            #pragma unroll
            for (int fn = 0; fn < 7; ++fn) {
                int n = fn * 16 + l15;
                int ol = (wave - 4) * 64 + fo * 16 + lg * 4;
                f32x4 a = acc[fo][fn];
                bf16x4 w = {(bf16)a[0], (bf16)a[1], (bf16)a[2], (bf16)a[3]};
                *(bf16x4*)(smem + n * SLAB_STRIDE + ol * 2) = w;
            }
    }
    __syncthreads();
    {   // c3p[c][m], pooled; 2 m per thread-unit (4B writes)
        bf16* dst = c3p + (size_t)b * CIN * MPAD + h2 * 28;
        for (int u = t; u < 3584; u += 512) {
            int c = u / 14, w2p = u - c * 14;
            bf16x2 o_;
            #pragma unroll
            for (int k = 0; k < 2; ++k) {
                int w2 = 2 * w2p + k;
                float p0 = (float)*(bf16*)(smem + (2 * w2)      * SLAB_STRIDE + c * 2);
                float p1 = (float)*(bf16*)(smem + (2 * w2 + 1)  * SLAB_STRIDE + c * 2);
                float p2 = (float)*(bf16*)(smem + (56 + 2 * w2) * SLAB_STRIDE + c * 2);
                float p3 = (float)*(bf16*)(smem + (57 + 2 * w2) * SLAB_STRIDE + c * 2);
                float mx = fmaxf(fmaxf(p0, p1), fmaxf(p2, p3));
                float av = (p0 + p1 + p2 + p3) * 0.25f;
                o_[k] = (bf16)(mx + av);
            }
            *(bf16x2*)(dst + (size_t)c * MPAD + 2 * w2p) = o_;
        }
    }
}

// ---------------------------------------------------------------------------
// k_attn: MFMA scores -> softmax -> MFMA PV -> gamma*refined + x  (unchanged)
// ---------------------------------------------------------------------------
__global__ __launch_bounds__(512, 2) void k_attn(
    const bf16* __restrict__ c2n,
    const bf16* __restrict__ c1pT,
    const bf16* __restrict__ c3p,
    const float* __restrict__ x,
    const float* __restrict__ gamma,
    float* __restrict__ out)
{
    const int nb = blockIdx.x, b = blockIdx.y;
    const int n0 = nb * 64;
    const int t = threadIdx.x;
    const int lane = t & 63, wave = t >> 6;
    const int l15 = lane & 15, lg = lane >> 4;
    const int wn = wave >> 2, wq = wave & 3;

    __shared__ __align__(16) unsigned char smem[114688];
    float* R = (float*)smem;

    bf16x8 afr[2][4];
    {
        const bf16* base = c2n + (size_t)b * NPIX * CHALF;
        #pragma unroll
        for (int fn = 0; fn < 2; ++fn) {
            int n = n0 + wn * 32 + fn * 16 + l15;
            #pragma unroll
            for (int k = 0; k < 4; ++k)
                afr[fn][k] = *(const bf16x8*)(base + (size_t)n * CHALF + k * 32 + lg * 8);
        }
    }
    f32x4 acc[2][14];
    #pragma unroll
    for (int fn = 0; fn < 2; ++fn)
        #pragma unroll
        for (int mf = 0; mf < 14; ++mf) {
            f32x4 z = {0.f, 0.f, 0.f, 0.f};
            acc[fn][mf] = z;
        }

    const bf16* c1b = c1pT + (size_t)b * MPAD * CHALF;
    for (int mf = 0; mf < 14; ++mf) {
        int m = wq * 224 + mf * 16 + l15;
        #pragma unroll
        for (int k = 0; k < 4; ++k) {
            bf16x8 bfr = *(const bf16x8*)(c1b + (size_t)m * CHALF + k * 32 + lg * 8);
            acc[0][mf] = __builtin_amdgcn_mfma_f32_16x16x32_bf16(afr[0][k], bfr, acc[0][mf], 0, 0, 0);
            acc[1][mf] = __builtin_amdgcn_mfma_f32_16x16x32_bf16(afr[1][k], bfr, acc[1][mf], 0, 0, 0);
        }
    }
    #pragma unroll
    for (int fn = 0; fn < 2; ++fn)
        #pragma unroll
        for (int mf = 0; mf < 14; ++mf) {
            int m = wq * 224 + mf * 16 + l15;
            #pragma unroll
            for (int r = 0; r < 4; ++r) {
                int n = wn * 32 + fn * 16 + lg * 4 + r;
                int byte = (n * 1792 + m * 2) ^ ((n & 7) << 4);
                *(bf16*)(smem + byte) = (bf16)acc[fn][mf][r];
            }
        }
    __syncthreads();

    for (int rr = 0; rr < 8; ++rr) {
        int n = wave * 8 + rr;
        int rowbase = n * 1792, sw = (n & 7) << 4;
        float v[13];
        float mx = -1e30f;
        #pragma unroll
        for (int i = 0; i < 13; ++i) {
            int m = lane + 64 * i;
            v[i] = (m < MPOOL) ? (float)*(const bf16*)(smem + ((rowbase + 2 * m) ^ sw))
                               : -1e30f;
            mx = fmaxf(mx, v[i]);
        }
        #pragma unroll
        for (int off = 32; off; off >>= 1) mx = fmaxf(mx, __shfl_xor(mx, off));
        float s = 0.f;
        float e[13];
        #pragma unroll
        for (int i = 0; i < 13; ++i) {
            int m = lane + 64 * i;
            e[i] = (m < MPOOL) ? __expf(v[i] - mx) : 0.f;
            s += e[i];
        }
        #pragma unroll
        for (int off = 32; off; off >>= 1) s += __shfl_xor(s, off);
        float ri = 1.f / s;
        #pragma unroll
        for (int i = 0; i < 14; ++i) {
            int m = lane + 64 * i;
            float pv = (i < 13) ? e[i] * ri : 0.f;
            *(bf16*)(smem + ((rowbase + 2 * m) ^ sw)) = (bf16)pv;
        }
    }
    __syncthreads();

    f32x4 acc2[2][4];
    #pragma unroll
    for (int fn = 0; fn < 2; ++fn)
        #pragma unroll
        for (int fc = 0; fc < 4; ++fc) {
            f32x4 z = {0.f, 0.f, 0.f, 0.f};
            acc2[fn][fc] = z;
        }
    const bf16* c3b = c3p + (size_t)b * CIN * MPAD;
    for (int ks = 0; ks < 28; ++ks) {
        int m0 = ks * 32 + lg * 8;
        bf16x8 af[2];
        #pragma unroll
        for (int fn = 0; fn < 2; ++fn) {
            int n = wn * 32 + fn * 16 + l15;
            int byte = (n * 1792 + m0 * 2) ^ ((n & 7) << 4);
            af[fn] = *(const bf16x8*)(smem + byte);
        }
        #pragma unroll
        for (int fc = 0; fc < 4; ++fc) {
            int c = wq * 64 + fc * 16 + l15;
            bf16x8 bfr = *(const bf16x8*)(c3b + (size_t)c * MPAD + m0);
            acc2[0][fc] = __builtin_amdgcn_mfma_f32_16x16x32_bf16(af[0], bfr, acc2[0][fc], 0, 0, 0);
            acc2[1][fc] = __builtin_amdgcn_mfma_f32_16x16x32_bf16(af[1], bfr, acc2[1][fc], 0, 0, 0);
        }
    }

    __syncthreads();
    #pragma unroll
    for (int fn = 0; fn < 2; ++fn)
        #pragma unroll
        for (int fc = 0; fc < 4; ++fc) {
            int c = wq * 64 + fc * 16 + l15;
            #pragma unroll
            for (int r = 0; r < 4; ++r) {
                int n = wn * 32 + fn * 16 + lg * 4 + r;
                R[n * 257 + c] = acc2[fn][fc][r];
            }
        }
    __syncthreads();
    const float g = gamma[0];
    const float* xb = x + (size_t)b * CIN * NPIX + n0;
    float* ob = out + (size_t)b * CIN * NPIX + n0;
    #pragma unroll 4
    for (int i = 0; i < 32; ++i) {
        int idx = t + i * 512;
        int c = idx >> 6, nn = idx & 63;
        size_t off = (size_t)c * NPIX + nn;
        ob[off] = g * R[nn * 257 + c] + xb[off];
    }
}

extern "C" void kernel_launch(void* const* d_in, const int* in_sizes, int n_in,
                              void* d_out, int out_size, void* d_ws, size_t ws_size,
                              hipStream_t stream) {
    const float* x     = (const float*)d_in[0];
    const float* W1    = (const float*)d_in[1];
    const float* W2    = (const float*)d_in[2];
    const float* W3    = (const float*)d_in[3];
    const float* gamma = (const float*)d_in[4];
    float* out = (float*)d_out;

    bf16* ws   = (bf16*)d_ws;
    bf16* Wcat = ws;                                       // 512*256
    bf16* c2n  = Wcat + (size_t)512 * 256;                 // 32*3136*128
    bf16* c1pT = c2n + (size_t)BATCH * NPIX * CHALF;       // 32*896*128
    bf16* c3p  = c1pT + (size_t)BATCH * MPAD * CHALF;      // 32*256*896

    k_cast<<<128, 256, 0, stream>>>(W1, W2, W3, Wcat);
    k_conv<<<dim3(28, BATCH), 512, 0, stream>>>(x, Wcat, c2n, c1pT, c3p);
    k_attn<<<dim3(49, BATCH), 512, 0, stream>>>(c2n, c1pT, c3p, x, gamma, out);
}